// Round 7
// baseline (309.473 us; speedup 1.0000x reference)
//
#include <hip/hip_runtime.h>
#include <stdint.h>
#include <stddef.h>

#define NB 2
#define NT 4096
#define NC 768
#define NH 12
#define ND 64

typedef unsigned short u16;
typedef __attribute__((ext_vector_type(4))) float f32x4;
typedef __attribute__((ext_vector_type(8))) unsigned short u16x8;
typedef __attribute__((ext_vector_type(4))) unsigned short u16x4;
typedef __attribute__((ext_vector_type(8))) __bf16 bf16x8;

__device__ __forceinline__ u16 f2bf(float f) {
  uint32_t u = __builtin_bit_cast(uint32_t, f);
  u += 0x7FFFu + ((u >> 16) & 1u);   // RTNE
  return (u16)(u >> 16);
}
__device__ __forceinline__ bf16x8 asbf(u16x8 v) { return __builtin_bit_cast(bf16x8, v); }

// pack two f32 -> two bf16, round-half-up: 3 VALU
__device__ __forceinline__ uint32_t pkbf(float a, float b) {
  uint32_t ua = __builtin_bit_cast(uint32_t, a) + 0x8000u;
  uint32_t ub = __builtin_bit_cast(uint32_t, b) + 0x8000u;
  return __builtin_amdgcn_perm(ub, ua, 0x07060302u);
}
// truncating pack (P only; numerator/denominator stay consistent): 1 VALU
__device__ __forceinline__ uint32_t pktr(float a, float b) {
  return __builtin_amdgcn_perm(__builtin_bit_cast(uint32_t, b),
                               __builtin_bit_cast(uint32_t, a), 0x07060302u);
}

// async global -> LDS, 16 B per lane (dest = wave-uniform base + lane*16)
__device__ __forceinline__ void glds16(const u16* g, u16* l) {
  __builtin_amdgcn_global_load_lds(
      (const __attribute__((address_space(1))) uint32_t*)g,
      (__attribute__((address_space(3))) uint32_t*)l, 16, 0, 0);
}

// ---------------- cast fp32 -> bf16 ----------------
__global__ void k_cast(const float* __restrict__ in, u16* __restrict__ out, int n4) {
  int i = blockIdx.x * blockDim.x + threadIdx.x;
  if (i < n4) {
    f32x4 v = ((const f32x4*)in)[i];
    u16x4 o;
    o[0] = f2bf(v[0]); o[1] = f2bf(v[1]); o[2] = f2bf(v[2]); o[3] = f2bf(v[3]);
    ((u16x4*)out)[i] = o;
  }
}

// -------- transpose + cast --------
__global__ void k_transpose(const float* __restrict__ in, u16* __restrict__ out,
                            int R, int Cn) {
  __shared__ float tile[32][33];
  int c0 = blockIdx.x * 32, r0 = blockIdx.y * 32;
  int tx = threadIdx.x & 31, ty = threadIdx.x >> 5;
  for (int i = ty; i < 32; i += 8)
    tile[i][tx] = in[(size_t)(r0 + i) * Cn + c0 + tx];
  __syncthreads();
  for (int i = ty; i < 32; i += 8)
    out[(size_t)(c0 + i) * R + r0 + tx] = f2bf(tile[tx][i]);
}

// -------- GEMM: C[M,N] = A[M,K] * Bt[N,K]^T --------
// m97-style: global_load_lds(16B) staging into XOR-swizzled unpadded LDS
// (stride 32 u16; phys colblock = cb ^ (row&3)). BK=32, 128x128 tile.
template <int EPI>
__global__ __launch_bounds__(256, 3)
void k_gemm_bt(const u16* __restrict__ A, const u16* __restrict__ Bt,
               int M, int N, int K,
               u16* __restrict__ o0, u16* __restrict__ o1, u16* __restrict__ o2,
               float* __restrict__ of) {
  __shared__ u16 As[128 * 32];
  __shared__ u16 Bs[128 * 32];
  const int tid = threadIdx.x;
  const int wave = tid >> 6, lane = tid & 63, quad = lane >> 4, lc = lane & 15;
  const int wm = (wave & 1) * 64, wn = (wave >> 1) * 64;
  const int bm = blockIdx.y * 128, bn = blockIdx.x * 128;

  // staging: wave w covers rows w*32..w*32+31 (2 chunks of 16 rows each)
  const int ri = lane >> 2;           // 0..15 row within chunk
  const int ci = lane & 3;            // 16B block within 64B row
  const int xb = ((ci ^ (ri & 3)) * 8);  // swizzled logical k-block (u16 offset)
  const u16* gA0 = A + (size_t)(bm + wave * 32 + ri) * K + xb;
  const u16* gA1 = A + (size_t)(bm + wave * 32 + 16 + ri) * K + xb;
  const u16* gB0 = Bt + (size_t)(bn + wave * 32 + ri) * K + xb;
  const u16* gB1 = Bt + (size_t)(bn + wave * 32 + 16 + ri) * K + xb;
  u16* lA0 = &As[(wave * 32) * 32 + lane * 8];
  u16* lA1 = &As[(wave * 32 + 16) * 32 + lane * 8];
  u16* lB0 = &Bs[(wave * 32) * 32 + lane * 8];
  u16* lB1 = &Bs[(wave * 32 + 16) * 32 + lane * 8];

  const int xr = (quad ^ (lc & 3)) * 8;  // swizzled fragment read offset

  f32x4 zv = {0.f, 0.f, 0.f, 0.f};
  f32x4 acc[4][4];
#pragma unroll
  for (int i = 0; i < 4; ++i)
#pragma unroll
    for (int j = 0; j < 4; ++j) acc[i][j] = zv;

  for (int k0 = 0; k0 < K; k0 += 32) {
    __syncthreads();                  // prior fragment reads done
    glds16(gA0 + k0, lA0);
    glds16(gA1 + k0, lA1);
    glds16(gB0 + k0, lB0);
    glds16(gB1 + k0, lB1);
    __syncthreads();                  // drain vmcnt, all waves staged

    bf16x8 af[4], bfv[4];
#pragma unroll
    for (int mi = 0; mi < 4; ++mi)
      af[mi] = asbf(*(const u16x8*)&As[(wm + mi * 16 + lc) * 32 + xr]);
#pragma unroll
    for (int ni = 0; ni < 4; ++ni)
      bfv[ni] = asbf(*(const u16x8*)&Bs[(wn + ni * 16 + lc) * 32 + xr]);
#pragma unroll
    for (int mi = 0; mi < 4; ++mi)
#pragma unroll
      for (int ni = 0; ni < 4; ++ni)
        acc[mi][ni] = __builtin_amdgcn_mfma_f32_16x16x32_bf16(af[mi], bfv[ni],
                                                              acc[mi][ni], 0, 0, 0);
  }

  const int mrow0 = bm + wm + quad * 4;
#pragma unroll
  for (int mi = 0; mi < 4; ++mi) {
    const int mbase = mrow0 + mi * 16;
#pragma unroll
    for (int ni = 0; ni < 4; ++ni) {
      const int n = bn + wn + ni * 16 + lc;
      if (EPI == 0) {
#pragma unroll
        for (int r = 0; r < 4; ++r)
          of[(size_t)(mbase + r) * N + n] = acc[mi][ni][r];
      } else {
        const int sect = n / NC;          // 0=q 1=k 2=v
        const int wn2 = n - sect * NC;
        const int h = wn2 >> 6, d = wn2 & 63;
        const int b = mbase >> 12;
        const int t = mbase & (NT - 1);
        const float sc = (sect == 0) ? 0.18033688011112042f : 1.0f;  // log2e/8
        if (sect == 2) {
          u16x4 pk;
#pragma unroll
          for (int r = 0; r < 4; ++r) pk[r] = f2bf(acc[mi][ni][r]);
          *(u16x4*)&o2[((size_t)(b * NH + h) * ND + d) * NT + t] = pk;
        } else {
          u16* dst = (sect == 0) ? o0 : o1;
#pragma unroll
          for (int r = 0; r < 4; ++r)
            dst[((size_t)(b * NH + h) * NT + (t + r)) * ND + d] =
                f2bf(acc[mi][ni][r] * sc);
        }
      }
    }
  }
}

// -------- flash attention, causal, merged dual Q-tiles, glds staging --------
// As round 6 (lockstep KV walk, ones-row computes l via MFMA, no partials)
// but K/V staged via global_load_lds into XOR-swizzled unpadded LDS
// (stride 64 u16; phys colblock = cb ^ (row&7)). 36.9 KB LDS -> 4 blocks/CU.
#define PSTR 72   // Ps stride (padded; register->LDS path keeps pad)
__global__ __launch_bounds__(256, 4)
void k_attn(const u16* __restrict__ Q, const u16* __restrict__ K,
            const u16* __restrict__ Vt, u16* __restrict__ Y) {
  __shared__ u16 Ks[64 * 64];          // [t][d] swizzled
  __shared__ u16 Vs[80 * 64];          // [d][t] swizzled; rows 64..79 static
  __shared__ u16 Ps[4 * 2 * 16 * PSTR];// per-wave, per-phase P^T [q][t]

  const int tid = threadIdx.x;
  const int wave = tid >> 6, lane = tid & 63, quad = lane >> 4, lc = lane & 15;
  const int bh = blockIdx.x >> 5, pair = blockIdx.x & 31;
  const int b = bh / NH, h = bh - b * NH;
  const u16* Qb = Q + (size_t)bh * NT * ND;
  const u16* Kb = K + (size_t)bh * NT * ND;
  const u16* Vb = Vt + (size_t)bh * ND * NT;

  // static Vs rows (constant per row -> swizzle-invariant): 64 = 1.0, rest 0
  for (int idx = tid; idx < 16 * 64; idx += 256) {
    int r = idx >> 6, c = idx & 63;
    Vs[(64 + r) * 64 + c] = (r == 0) ? (u16)0x3F80 : (u16)0;
  }

  const int qwA = pair * 64 + wave * 16;
  const int qwB = (63 - pair) * 64 + wave * 16;
  u16* PsA = &Ps[(wave * 2 + 0) * 16 * PSTR];
  u16* PsB = &Ps[(wave * 2 + 1) * 16 * PSTR];

  // Q as B-operand fragments (scale log2(e)/8 pre-folded into Q)
  bf16x8 bqA[2], bqB[2];
#pragma unroll
  for (int ks = 0; ks < 2; ++ks) {
    bqA[ks] = asbf(*(const u16x8*)(Qb + (size_t)(qwA + lc) * ND + ks * 32 + quad * 8));
    bqB[ks] = asbf(*(const u16x8*)(Qb + (size_t)(qwB + lc) * ND + ks * 32 + quad * 8));
  }

  f32x4 zv = {0.f, 0.f, 0.f, 0.f};
  f32x4 oA[5], oB[5];                 // O^T [dtile 0..3], [4] = l row
#pragma unroll
  for (int dt = 0; dt < 5; ++dt) { oA[dt] = zv; oB[dt] = zv; }

  // staging lane constants: wave w covers rows w*16..w*16+15 (2 chunks of 8)
  const int sri = lane >> 3;          // 0..7 row within chunk
  const int sci = lane & 7;           // 16B block within 128B row
  const int sxb = ((sci ^ sri) * 8);  // swizzled logical t/d-block (u16)
  const u16* gK0 = Kb + (size_t)(wave * 16 + sri) * ND + sxb;
  const u16* gK1 = Kb + (size_t)(wave * 16 + 8 + sri) * ND + sxb;
  const u16* gV0 = Vb + (size_t)(wave * 16 + sri) * NT + sxb;
  const u16* gV1 = Vb + (size_t)(wave * 16 + 8 + sri) * NT + sxb;
  u16* lK0 = &Ks[(wave * 16) * 64 + lane * 8];
  u16* lK1 = &Ks[(wave * 16 + 8) * 64 + lane * 8];
  u16* lV0 = &Vs[(wave * 16) * 64 + lane * 8];
  u16* lV1 = &Vs[(wave * 16 + 8) * 64 + lane * 8];

  const int xr0 = (quad ^ (lc & 7)) * 8;   // frag read offset, ks=0
  const int xr1 = xr0 ^ 32;                // ks=1 (block 4+quad = quad^4)

  const int ntiles = 64 - pair;

#pragma unroll 1
  for (int tau = 0; tau < ntiles; ++tau) {
    const int t0 = tau * 64;
    __syncthreads();                  // prior tile's LDS reads done
    glds16(gK0 + (size_t)t0 * ND, lK0);
    glds16(gK1 + (size_t)t0 * ND, lK1);
    glds16(gV0 + t0, lV0);
    glds16(gV1 + t0, lV1);
    __syncthreads();                  // drain vmcnt, all waves staged

    const bool actA = (tau <= pair);  // block-uniform

    // S^T = K Q^T for both phases, sharing K fragments
    f32x4 sA[4], sB[4];
#pragma unroll
    for (int mt = 0; mt < 4; ++mt) { sA[mt] = zv; sB[mt] = zv; }
#pragma unroll
    for (int ks = 0; ks < 2; ++ks) {
      const int xo = ks ? xr1 : xr0;
      bf16x8 ak[4];
#pragma unroll
      for (int mt = 0; mt < 4; ++mt)
        ak[mt] = asbf(*(const u16x8*)&Ks[(mt * 16 + lc) * 64 + xo]);
      if (actA) {
#pragma unroll
        for (int mt = 0; mt < 4; ++mt)
          sA[mt] = __builtin_amdgcn_mfma_f32_16x16x32_bf16(ak[mt], bqA[ks], sA[mt], 0, 0, 0);
      }
#pragma unroll
      for (int mt = 0; mt < 4; ++mt)
        sB[mt] = __builtin_amdgcn_mfma_f32_16x16x32_bf16(ak[mt], bqB[ks], sB[mt], 0, 0, 0);
    }

    // exp2 + truncating pack -> Ps (P^T rows = q = lc)
    if (actA) {
      const bool mskA = (tau == pair);
#pragma unroll
      for (int mt = 0; mt < 4; ++mt) {
        float e[4];
#pragma unroll
        for (int r = 0; r < 4; ++r) {
          float v = sA[mt][r];
          if (mskA) {
            int tg = t0 + mt * 16 + quad * 4 + r;
            v = (tg > qwA + lc) ? -1e30f : v;
          }
          e[r] = exp2f(v);
        }
        uint2 w;
        w.x = pktr(e[0], e[1]);
        w.y = pktr(e[2], e[3]);
        *(uint2*)&PsA[lc * PSTR + mt * 16 + quad * 4] = w;
      }
    }
    {
      const bool mskB = (tau == ntiles - 1);
#pragma unroll
      for (int mt = 0; mt < 4; ++mt) {
        float e[4];
#pragma unroll
        for (int r = 0; r < 4; ++r) {
          float v = sB[mt][r];
          if (mskB) {
            int tg = t0 + mt * 16 + quad * 4 + r;
            v = (tg > qwB + lc) ? -1e30f : v;
          }
          e[r] = exp2f(v);
        }
        uint2 w;
        w.x = pktr(e[0], e[1]);
        w.y = pktr(e[2], e[3]);
        *(uint2*)&PsB[lc * PSTR + mt * 16 + quad * 4] = w;
      }
    }

    // O^T += V^T P^T for both phases, sharing V fragments
#pragma unroll
    for (int ks = 0; ks < 2; ++ks) {
      const int xo = ks ? xr1 : xr0;
      bf16x8 av[5];
#pragma unroll
      for (int dt = 0; dt < 5; ++dt)
        av[dt] = asbf(*(const u16x8*)&Vs[(dt * 16 + lc) * 64 + xo]);
      if (actA) {
        bf16x8 bp = asbf(*(const u16x8*)&PsA[lc * PSTR + ks * 32 + quad * 8]);
#pragma unroll
        for (int dt = 0; dt < 5; ++dt)
          oA[dt] = __builtin_amdgcn_mfma_f32_16x16x32_bf16(av[dt], bp, oA[dt], 0, 0, 0);
      }
      {
        bf16x8 bp = asbf(*(const u16x8*)&PsB[lc * PSTR + ks * 32 + quad * 8]);
#pragma unroll
        for (int dt = 0; dt < 5; ++dt)
          oB[dt] = __builtin_amdgcn_mfma_f32_16x16x32_bf16(av[dt], bp, oB[dt], 0, 0, 0);
      }
    }
  }

  // epilogue: l = row 64 of O^T (quad 0, reg 0, lane lc); normalize, write Y
#pragma unroll
  for (int phx = 0; phx < 2; ++phx) {
    const f32x4* o = phx ? oB : oA;
    const int qg = (phx ? qwB : qwA) + lc;
    float l = __shfl(o[4][0], lc);
    float inv = 1.f / l;
    u16* yrow = Y + (size_t)(b * NT + qg) * NC + h * 64;
#pragma unroll
    for (int dt = 0; dt < 4; ++dt) {
      uint2 w;
      w.x = pkbf(o[dt][0] * inv, o[dt][1] * inv);
      w.y = pkbf(o[dt][2] * inv, o[dt][3] * inv);
      *(uint2*)&yrow[dt * 16 + quad * 4] = w;
    }
  }
}

extern "C" void kernel_launch(void* const* d_in, const int* in_sizes, int n_in,
                              void* d_out, int out_size, void* d_ws, size_t ws_size,
                              hipStream_t stream) {
  (void)in_sizes; (void)n_in; (void)out_size; (void)ws_size;
  const float* x = (const float*)d_in[0];
  const float* w_qkv = (const float*)d_in[1];
  const float* w_out = (const float*)d_in[2];
  float* out = (float*)d_out;

  u16* ws = (u16*)d_ws;
  const size_t XE = (size_t)NB * NT * NC;       // 6291456 elements
  u16* xb  = ws;
  u16* wqT = xb + XE;
  u16* woT = wqT + (size_t)3 * NC * NC;
  u16* Qb  = woT + (size_t)NC * NC;
  u16* Kb  = Qb + XE;
  u16* Vtb = Kb + XE;
  u16* yb  = Vtb + XE;

  k_cast<<<(int)(XE / 4 / 256), 256, 0, stream>>>(x, xb, (int)(XE / 4));
  k_transpose<<<dim3(3 * NC / 32, NC / 32), 256, 0, stream>>>(w_qkv, wqT, NC, 3 * NC);
  k_transpose<<<dim3(NC / 32, NC / 32), 256, 0, stream>>>(w_out, woT, NC, NC);
  k_gemm_bt<1><<<dim3(3 * NC / 128, NB * NT / 128), 256, 0, stream>>>(
      xb, wqT, NB * NT, 3 * NC, NC, Qb, Kb, Vtb, nullptr);
  k_attn<<<dim3(32 * NB * NH), 256, 0, stream>>>(Qb, Kb, Vtb, yb);
  k_gemm_bt<0><<<dim3(NC / 128, NB * NT / 128), 256, 0, stream>>>(
      yb, woT, NB * NT, NC, NC, nullptr, nullptr, nullptr, out);
}